// Round 3
// baseline (1727.995 us; speedup 1.0000x reference)
//
#include <hip/hip_runtime.h>
#include <hip/hip_bf16.h>

#define D 64
#define RPB 32                 // rows per bucket
#define ACC_ELEMS (RPB * D)    // 2048 floats = 8 KB LDS

typedef unsigned long long ull;

// ---------------- fallback: round-1 atomic kernel ----------------
__global__ __launch_bounds__(256) void spmm_atomic_kernel(
    const float* __restrict__ x,
    const int*   __restrict__ edge_row,
    const int*   __restrict__ edge_col,
    const float* __restrict__ edge_val,
    float*       __restrict__ out,
    int n_edges)
{
    const int gtid = blockIdx.x * blockDim.x + threadIdx.x;
    const int wave = gtid >> 6;
    const int lane = threadIdx.x & 63;
    if (wave >= n_edges) return;
    const int   r = edge_row[wave];
    const int   c = edge_col[wave];
    const float v = edge_val[wave];
    atomicAdd(&out[(size_t)r * D + lane], v * x[(size_t)c * D + lane]);
}

// ---------------- bucket histogram: counts[row>>5]++ ----------------
__global__ void hist_kernel(const int* __restrict__ rows,
                            int* __restrict__ counts, int n_edges)
{
    int i = blockIdx.x * blockDim.x + threadIdx.x;
    if (i < n_edges) atomicAdd(&counts[rows[i] >> 5], 1);
}

// ---------------- single-block exclusive scan over n_buckets (<=8192) ----------------
__global__ __launch_bounds__(1024) void scan_kernel(
    const int* __restrict__ counts,
    int* __restrict__ offsets,   // n_buckets + 1
    int* __restrict__ cursor,    // n_buckets
    int n_buckets, int ipt)      // ipt <= 8
{
    __shared__ int s[1024];
    const int t = threadIdx.x;
    const int base = t * ipt;
    int vexcl[8];
    int sum = 0;
    #pragma unroll
    for (int k = 0; k < 8; ++k) {
        if (k < ipt) {
            int i = base + k;
            int c = (i < n_buckets) ? counts[i] : 0;
            vexcl[k] = sum;
            sum += c;
        }
    }
    s[t] = sum;
    for (int off = 1; off < 1024; off <<= 1) {
        __syncthreads();
        int v = (t >= off) ? s[t - off] : 0;
        __syncthreads();
        s[t] += v;
    }
    const int texcl = s[t] - sum;  // exclusive prefix of this thread's chunk
    #pragma unroll
    for (int k = 0; k < 8; ++k) {
        if (k < ipt) {
            int i = base + k;
            if (i < n_buckets) {
                int o = texcl + vexcl[k];
                offsets[i] = o;
                cursor[i]  = o;
            }
        }
    }
    if (t == 1023) offsets[n_buckets] = s[1023];  // grand total
}

// ---------------- scatter edges into bucket-append streams ----------------
// record = [ val:f32 (hi32) | localrow:bits24-28, col:bits0-23 (lo32) ]
__global__ void scatter_kernel(const int* __restrict__ rows,
                               const int* __restrict__ cols,
                               const float* __restrict__ vals,
                               int* __restrict__ cursor,
                               ull* __restrict__ recs,
                               int n_edges)
{
    int i = blockIdx.x * blockDim.x + threadIdx.x;
    if (i >= n_edges) return;
    const int   r = rows[i];
    const int   c = cols[i];
    const float v = vals[i];
    const int   b = r >> 5;
    const unsigned packed = ((unsigned)(r & 31) << 24) | (unsigned)c;
    const int pos = atomicAdd(&cursor[b], 1);
    recs[pos] = ((ull)__float_as_uint(v) << 32) | (ull)packed;
}

// ---------------- bucket accumulate: one block per bucket ----------------
__global__ __launch_bounds__(256) void spmm_bucket_kernel(
    const float* __restrict__ x,
    const int*   __restrict__ offsets,
    const ull*   __restrict__ recs,
    float*       __restrict__ out,
    int n_nodes)
{
    __shared__ float acc[ACC_ELEMS];
    const int t = threadIdx.x;
    const int b = blockIdx.x;

    float4* acc4 = (float4*)acc;
    #pragma unroll
    for (int i = t; i < ACC_ELEMS / 4; i += 256)
        acc4[i] = make_float4(0.f, 0.f, 0.f, 0.f);
    __syncthreads();

    const int bs = offsets[b];
    const int be = offsets[b + 1];
    const int lane = t & 63;
    // force wave id into SGPR so record reads are wave-uniform (scalar loads)
    const int w = __builtin_amdgcn_readfirstlane(t >> 6);

    const int cnt = be - bs;
    const int per = (cnt + 3) >> 2;
    int j    = bs + w * per;
    int jend = j + per;
    if (jend > be) jend = be;
    if (j > be)    j = be;

    // 8-wide software pipeline: 8 independent x-gathers in flight
    for (; j + 8 <= jend; j += 8) {
        ull r[8];
        #pragma unroll
        for (int k = 0; k < 8; ++k) r[k] = recs[j + k];
        float xv[8], vv[8];
        int aa[8];
        #pragma unroll
        for (int k = 0; k < 8; ++k) {
            const unsigned p = (unsigned)r[k];
            vv[k] = __uint_as_float((unsigned)(r[k] >> 32));
            const int c = (int)(p & 0xFFFFFF);
            aa[k] = (int)(p >> 24) * D + lane;
            xv[k] = x[(size_t)c * D + lane];
        }
        #pragma unroll
        for (int k = 0; k < 8; ++k)
            atomicAdd(&acc[aa[k]], vv[k] * xv[k]);
    }
    for (; j < jend; ++j) {
        const ull rr = recs[j];
        const unsigned p = (unsigned)rr;
        const float v = __uint_as_float((unsigned)(rr >> 32));
        const int c = (int)(p & 0xFFFFFF);
        const int a = (int)(p >> 24) * D + lane;
        atomicAdd(&acc[a], v * x[(size_t)c * D + lane]);
    }
    __syncthreads();

    // coalesced float4 writeback; every out row belongs to exactly one bucket
    const float4* accr = (const float4*)acc;
    float4* out4 = (float4*)out;
    const size_t obase = (size_t)b * (ACC_ELEMS / 4);
    #pragma unroll
    for (int i = t; i < ACC_ELEMS / 4; i += 256) {
        const int row = b * RPB + (i >> 4);
        if (row < n_nodes) out4[obase + i] = accr[i];
    }
}

static inline size_t align16(size_t v) { return (v + 15) & ~(size_t)15; }

extern "C" void kernel_launch(void* const* d_in, const int* in_sizes, int n_in,
                              void* d_out, int out_size, void* d_ws, size_t ws_size,
                              hipStream_t stream)
{
    // setup_inputs order: t, x, edge_row, edge_col, edge_val
    const float* x        = (const float*)d_in[1];
    const int*   edge_row = (const int*)d_in[2];
    const int*   edge_col = (const int*)d_in[3];
    const float* edge_val = (const float*)d_in[4];
    float*       out      = (float*)d_out;

    const int n_edges = in_sizes[2];
    const int n_nodes = out_size / D;
    const int n_buckets = (n_nodes + RPB - 1) / RPB;
    const int ipt = (n_buckets + 1023) / 1024;

    // workspace carve: records first (8B-aligned), then counters
    const size_t off_recs    = 0;                                             // n_edges * 8
    const size_t off_counts  = align16(off_recs + (size_t)n_edges * 8);       // n_buckets ints
    const size_t off_offsets = align16(off_counts + (size_t)n_buckets * 4);   // n_buckets+1 ints
    const size_t off_cursor  = align16(off_offsets + (size_t)(n_buckets + 1) * 4); // n_buckets ints
    const size_t ws_needed   = off_cursor + (size_t)n_buckets * 4;

    if (ws_size < ws_needed || ipt > 8 || n_nodes > (1 << 24)) {
        hipMemsetAsync(out, 0, (size_t)out_size * sizeof(float), stream);
        const int n_blocks = (n_edges + 3) / 4;
        spmm_atomic_kernel<<<n_blocks, 256, 0, stream>>>(
            x, edge_row, edge_col, edge_val, out, n_edges);
        return;
    }

    char* ws = (char*)d_ws;
    ull*  recs    = (ull*)(ws + off_recs);
    int*  counts  = (int*)(ws + off_counts);
    int*  offsets = (int*)(ws + off_offsets);
    int*  cursor  = (int*)(ws + off_cursor);

    hipMemsetAsync(counts, 0, (size_t)n_buckets * sizeof(int), stream);

    const int eb = (n_edges + 255) / 256;
    hist_kernel<<<eb, 256, 0, stream>>>(edge_row, counts, n_edges);
    scan_kernel<<<1, 1024, 0, stream>>>(counts, offsets, cursor, n_buckets, ipt);
    scatter_kernel<<<eb, 256, 0, stream>>>(edge_row, edge_col, edge_val,
                                           cursor, recs, n_edges);
    spmm_bucket_kernel<<<n_buckets, 256, 0, stream>>>(x, offsets, recs, out, n_nodes);
}